// Round 1
// baseline (681.506 us; speedup 1.0000x reference)
//
#include <hip/hip_runtime.h>
#include <hip/hip_bf16.h>

typedef __attribute__((ext_vector_type(8))) short bf16x8;
typedef __attribute__((ext_vector_type(4))) float f32x4;

#define NN 8192
#define DF 256
#define BM 32
#define BK 64
#define KSPLIT 2
#define KCH (NN / KSPLIT)
#define NT (KCH / BK)

static __device__ __forceinline__ unsigned short f2bf(float f) {
  union { float f; unsigned u; } v; v.f = f;
  unsigned r = (v.u + 0x7FFFu + ((v.u >> 16) & 1u)) >> 16;
  return (unsigned short)r;
}

// ---- kernel 1: h2[j] = dot(input[j,:], A[0:256])  (one wave per row)
__global__ void k_h2(const float* __restrict__ input, const float* __restrict__ A,
                     float* __restrict__ h2) {
  int gw = (blockIdx.x * blockDim.x + threadIdx.x) >> 6;  // row j
  int lane = threadIdx.x & 63;
  float4 x = *reinterpret_cast<const float4*>(&input[(size_t)gw * DF + lane * 4]);
  float4 a = *reinterpret_cast<const float4*>(&A[lane * 4]);
  float p = x.x * a.x + x.y * a.y + x.z * a.z + x.w * a.w;
#pragma unroll
  for (int off = 32; off > 0; off >>= 1) p += __shfl_down(p, off, 64);
  if (lane == 0) h2[gw] = p;
}

// ---- kernel 2: M = max(h2)   (single block)
__global__ void k_max(const float* __restrict__ h2, float* __restrict__ Mout) {
  __shared__ float sm[4];
  float m = -3.0e38f;
  for (int i = threadIdx.x; i < NN; i += 256) m = fmaxf(m, h2[i]);
#pragma unroll
  for (int off = 32; off > 0; off >>= 1) m = fmaxf(m, __shfl_down(m, off, 64));
  int lane = threadIdx.x & 63, wid = threadIdx.x >> 6;
  if (lane == 0) sm[wid] = m;
  __syncthreads();
  if (threadIdx.x == 0)
    Mout[0] = fmaxf(fmaxf(sm[0], sm[1]), fmaxf(sm[2], sm[3]));
}

// ---- kernel 3: sF (fp32) and sT (bf16)
__global__ void k_s(const float* __restrict__ h2, const float* __restrict__ Mp,
                    float* __restrict__ sF, unsigned short* __restrict__ sT) {
  int j = blockIdx.x * 256 + threadIdx.x;
  float s = expf(h2[j] - Mp[0]);
  sF[j] = s;
  sT[j] = f2bf(s);
}

// ---- kernel 4: XsT[c][j] = bf16(sF[j] * input[j][c])   (transposed, bf16)
__global__ void k_xst(const float* __restrict__ input, const float* __restrict__ sF,
                      unsigned short* __restrict__ XsT) {
  int b = blockIdx.x;
  int jb = b >> 2, cb = b & 3;
  int t = threadIdx.x;
  int j0 = jb * 64 + (t & 15) * 4;
  int c0 = cb * 64 + (t >> 4) * 4;
  float4 x[4]; float s[4];
#pragma unroll
  for (int ii = 0; ii < 4; ii++) {
    x[ii] = *reinterpret_cast<const float4*>(&input[(size_t)(j0 + ii) * DF + c0]);
    s[ii] = sF[j0 + ii];
  }
#pragma unroll
  for (int q = 0; q < 4; q++) {
    ushort4 o;
    o.x = f2bf(reinterpret_cast<const float*>(&x[0])[q] * s[0]);
    o.y = f2bf(reinterpret_cast<const float*>(&x[1])[q] * s[1]);
    o.z = f2bf(reinterpret_cast<const float*>(&x[2])[q] * s[2]);
    o.w = f2bf(reinterpret_cast<const float*>(&x[3])[q] * s[3]);
    *reinterpret_cast<ushort4*>(&XsT[(size_t)(c0 + q) * NN + j0]) = o;
  }
}

// ---- kernel 5: numerator partials (+ fused denominator) via MFMA
// C[kidx] = adj[:, kchunk] @ XsT[:, kchunk]^T ; denom[kidx] = adj[:, kchunk] @ s
__global__ __launch_bounds__(512, 4) void k_gemm(
    const int* __restrict__ adj, const unsigned short* __restrict__ XsT,
    const unsigned short* __restrict__ sT, float* __restrict__ C0,
    float* __restrict__ C1, float* __restrict__ denomPart) {
  __shared__ __align__(16) char Alds[BM * BK * 2];   // 4KB, swizzled [32][64] bf16
  __shared__ __align__(16) char Blds[DF * BK * 2];   // 32KB, swizzled [256][64] bf16

  const int tid = threadIdx.x;
  const int lane = tid & 63;
  const int wid = tid >> 6;
  const int wrow = wid >> 2;   // 0..1 -> 16 rows each
  const int wcol = wid & 3;    // 0..3 -> 64 cols each
  const int bx = blockIdx.x;
  const int kidx = bx & (KSPLIT - 1);
  const int rb = bx >> 1;      // 0..255
  const int kbeg = kidx * KCH;

  float* __restrict__ Cout = kidx ? C1 : C0;

  // A staging: thread -> (row, 4 int32 cols)
  const int ar = tid >> 4;            // 0..31
  const int ac4 = (tid & 15) * 4;     // 0..60
  const size_t a_base = (size_t)(rb * BM + ar) * NN + ac4;
  const int a_lds_off = (ar * (BK * 2) + ac4 * 2) ^ ((ar & 7) << 4);

  // B staging: 4 chunks of 16B per thread
  size_t b_goff[4]; int b_lds_off[4];
#pragma unroll
  for (int i = 0; i < 4; i++) {
    int chunk = i * 512 + tid;
    int c = chunk >> 3, slot = chunk & 7;
    b_goff[i] = (size_t)c * NN + slot * 8;
    b_lds_off[i] = (c * (BK * 2) + slot * 16) ^ ((c & 7) << 4);
  }

  int4 pfA; int4 pfB[4];
  auto issue = [&](int k0) {
    pfA = *reinterpret_cast<const int4*>(&adj[a_base + k0]);
#pragma unroll
    for (int i = 0; i < 4; i++)
      pfB[i] = *reinterpret_cast<const int4*>(&XsT[b_goff[i] + k0]);
  };
  auto commit = [&]() {
    ushort4 ab;
    ab.x = pfA.x > 0 ? 0x3F80 : 0;
    ab.y = pfA.y > 0 ? 0x3F80 : 0;
    ab.z = pfA.z > 0 ? 0x3F80 : 0;
    ab.w = pfA.w > 0 ? 0x3F80 : 0;
    *reinterpret_cast<ushort4*>(Alds + a_lds_off) = ab;
#pragma unroll
    for (int i = 0; i < 4; i++)
      *reinterpret_cast<int4*>(Blds + b_lds_off[i]) = pfB[i];
  };

  f32x4 acc[4] = {{0,0,0,0},{0,0,0,0},{0,0,0,0},{0,0,0,0}};
  f32x4 accD = {0, 0, 0, 0};

  const int arow = wrow * 16 + (lane & 15);
  const int kslot = (lane >> 4) * 16;     // byte offset of 8-bf16 chunk

  issue(kbeg);
  commit();
  __syncthreads();

  for (int t = 0; t < NT; t++) {
    if (t + 1 < NT) issue(kbeg + (t + 1) * BK);
#pragma unroll
    for (int kk = 0; kk < 2; kk++) {
      bf16x8 af = *reinterpret_cast<const bf16x8*>(
          Alds + ((arow * (BK * 2) + kk * 64 + kslot) ^ ((arow & 7) << 4)));
#pragma unroll
      for (int n = 0; n < 4; n++) {
        int c = wcol * 64 + n * 16 + (lane & 15);
        bf16x8 bfr = *reinterpret_cast<const bf16x8*>(
            Blds + ((c * (BK * 2) + kk * 64 + kslot) ^ ((c & 7) << 4)));
        acc[n] = __builtin_amdgcn_mfma_f32_16x16x32_bf16(af, bfr, acc[n], 0, 0, 0);
      }
      if (wcol == 0) {
        bf16x8 sv = {0, 0, 0, 0, 0, 0, 0, 0};
        if ((lane & 15) == 0)
          sv = *reinterpret_cast<const bf16x8*>(
              &sT[kbeg + t * BK + kk * 32 + (lane >> 4) * 8]);
        accD = __builtin_amdgcn_mfma_f32_16x16x32_bf16(af, sv, accD, 0, 0, 0);
      }
    }
    __syncthreads();
    if (t + 1 < NT) { commit(); __syncthreads(); }
  }

  // write numerator partial (C layout: col = lane&15, row = (lane>>4)*4 + q)
  const int row0 = rb * BM + wrow * 16 + (lane >> 4) * 4;
#pragma unroll
  for (int n = 0; n < 4; n++) {
    int col = wcol * 64 + n * 16 + (lane & 15);
#pragma unroll
    for (int q = 0; q < 4; q++)
      Cout[(size_t)(row0 + q) * DF + col] = acc[n][q];
  }
  if (wcol == 0 && (lane & 15) == 0) {
#pragma unroll
    for (int q = 0; q < 4; q++)
      denomPart[kidx * NN + row0 + q] = accD[q];
  }
}

// ---- kernel 6: out = (C0 + C1) / denom   (in place: C0 == d_out)
__global__ void k_norm(float* __restrict__ out, const float* __restrict__ C1,
                       const float* __restrict__ denomPart) {
  int e4 = blockIdx.x * 256 + threadIdx.x;      // 0 .. 524287
  size_t base = (size_t)e4 * 4;
  int row = (int)(base >> 8);
  float4 a = *reinterpret_cast<const float4*>(&out[base]);
  float4 b = *reinterpret_cast<const float4*>(&C1[base]);
  float inv = 1.0f / (denomPart[row] + denomPart[NN + row]);
  float4 r;
  r.x = (a.x + b.x) * inv;
  r.y = (a.y + b.y) * inv;
  r.z = (a.z + b.z) * inv;
  r.w = (a.w + b.w) * inv;
  *reinterpret_cast<float4*>(&out[base]) = r;
}

extern "C" void kernel_launch(void* const* d_in, const int* in_sizes, int n_in,
                              void* d_out, int out_size, void* d_ws, size_t ws_size,
                              hipStream_t stream) {
  const float* input = (const float*)d_in[0];
  const int* adj = (const int*)d_in[1];
  const float* A = (const float*)d_in[2];
  float* out = (float*)d_out;

  char* ws = (char*)d_ws;
  float* h2 = (float*)(ws + 0);                         // 32 KB
  float* Mv = (float*)(ws + 32768);                     // 256 B
  float* sF = (float*)(ws + 33024);                     // 32 KB
  unsigned short* sT = (unsigned short*)(ws + 65792);   // 16 KB
  unsigned short* XsT = (unsigned short*)(ws + 82176);  // 4 MB
  float* C1 = (float*)(ws + 82176 + 4194304);           // 8 MB
  float* denomPart = (float*)(ws + 82176 + 4194304 + 8388608);  // 64 KB

  k_h2<<<dim3(NN / 4), dim3(256), 0, stream>>>(input, A, h2);
  k_max<<<dim3(1), dim3(256), 0, stream>>>(h2, Mv);
  k_s<<<dim3(NN / 256), dim3(256), 0, stream>>>(h2, Mv, sF, sT);
  k_xst<<<dim3((NN / 64) * (DF / 64)), dim3(256), 0, stream>>>(input, sF, XsT);
  k_gemm<<<dim3((NN / BM) * KSPLIT), dim3(512), 0, stream>>>(adj, XsT, sT, out, C1,
                                                             denomPart);
  k_norm<<<dim3(NN * DF / 1024), dim3(256), 0, stream>>>(out, C1, denomPart);
}

// Round 2
// 680.994 us; speedup vs baseline: 1.0008x; 1.0008x over previous
//
#include <hip/hip_runtime.h>
#include <hip/hip_bf16.h>

typedef __attribute__((ext_vector_type(8))) short bf16x8;
typedef __attribute__((ext_vector_type(4))) float f32x4;

#define NN 8192
#define DF 256
#define BM 32
#define BK 64
#define KSPLIT 2
#define KCH (NN / KSPLIT)
#define NT (KCH / BK)

static __device__ __forceinline__ unsigned short f2bf(float f) {
  union { float f; unsigned u; } v; v.f = f;
  unsigned r = (v.u + 0x7FFFu + ((v.u >> 16) & 1u)) >> 16;
  return (unsigned short)r;
}

// ---- kernel 1: h2[j] = dot(input[j,:], A[0:256])  (one wave per row)
__global__ void k_h2(const float* __restrict__ input, const float* __restrict__ A,
                     float* __restrict__ h2) {
  int gw = (blockIdx.x * blockDim.x + threadIdx.x) >> 6;  // row j
  int lane = threadIdx.x & 63;
  float4 x = *reinterpret_cast<const float4*>(&input[(size_t)gw * DF + lane * 4]);
  float4 a = *reinterpret_cast<const float4*>(&A[lane * 4]);
  float p = x.x * a.x + x.y * a.y + x.z * a.z + x.w * a.w;
#pragma unroll
  for (int off = 32; off > 0; off >>= 1) p += __shfl_down(p, off, 64);
  if (lane == 0) h2[gw] = p;
}

// ---- kernel 2: M = max(h2)   (single block)
__global__ void k_max(const float* __restrict__ h2, float* __restrict__ Mout) {
  __shared__ float sm[4];
  float m = -3.0e38f;
  for (int i = threadIdx.x; i < NN; i += 256) m = fmaxf(m, h2[i]);
#pragma unroll
  for (int off = 32; off > 0; off >>= 1) m = fmaxf(m, __shfl_down(m, off, 64));
  int lane = threadIdx.x & 63, wid = threadIdx.x >> 6;
  if (lane == 0) sm[wid] = m;
  __syncthreads();
  if (threadIdx.x == 0)
    Mout[0] = fmaxf(fmaxf(sm[0], sm[1]), fmaxf(sm[2], sm[3]));
}

// ---- kernel 3: sF (fp32) and sT (bf16)
__global__ void k_s(const float* __restrict__ h2, const float* __restrict__ Mp,
                    float* __restrict__ sF, unsigned short* __restrict__ sT) {
  int j = blockIdx.x * 256 + threadIdx.x;
  float s = expf(h2[j] - Mp[0]);
  sF[j] = s;
  sT[j] = f2bf(s);
}

// ---- kernel 4: XsT[c][j] = bf16(sF[j] * input[j][c])   (transposed, bf16)
__global__ void k_xst(const float* __restrict__ input, const float* __restrict__ sF,
                      unsigned short* __restrict__ XsT) {
  int b = blockIdx.x;
  int jb = b >> 2, cb = b & 3;
  int t = threadIdx.x;
  int j0 = jb * 64 + (t & 15) * 4;
  int c0 = cb * 64 + (t >> 4) * 4;
  float4 x[4]; float s[4];
#pragma unroll
  for (int ii = 0; ii < 4; ii++) {
    x[ii] = *reinterpret_cast<const float4*>(&input[(size_t)(j0 + ii) * DF + c0]);
    s[ii] = sF[j0 + ii];
  }
#pragma unroll
  for (int q = 0; q < 4; q++) {
    ushort4 o;
    o.x = f2bf(reinterpret_cast<const float*>(&x[0])[q] * s[0]);
    o.y = f2bf(reinterpret_cast<const float*>(&x[1])[q] * s[1]);
    o.z = f2bf(reinterpret_cast<const float*>(&x[2])[q] * s[2]);
    o.w = f2bf(reinterpret_cast<const float*>(&x[3])[q] * s[3]);
    *reinterpret_cast<ushort4*>(&XsT[(size_t)(c0 + q) * NN + j0]) = o;
  }
}

// ---- kernel 5: numerator partials (+ fused denominator) via MFMA
// C[kidx] = adj[:, kchunk] @ XsT[:, kchunk]^T ; denom[kidx] = adj[:, kchunk] @ s
__global__ __launch_bounds__(512, 2) void k_gemm(
    const int* __restrict__ adj, const unsigned short* __restrict__ XsT,
    const unsigned short* __restrict__ sT, float* __restrict__ C0,
    float* __restrict__ C1, float* __restrict__ denomPart) {
  __shared__ __align__(16) char Alds[BM * BK * 2];   // 4KB, swizzled [32][64] bf16
  __shared__ __align__(16) char Blds[DF * BK * 2];   // 32KB, swizzled [256][64] bf16

  const int tid = threadIdx.x;
  const int lane = tid & 63;
  const int wid = tid >> 6;
  const int wrow = wid >> 2;   // 0..1 -> 16 rows each
  const int wcol = wid & 3;    // 0..3 -> 64 cols each
  const int bx = blockIdx.x;
  const int kidx = bx & (KSPLIT - 1);
  const int rb = bx >> 1;      // 0..255
  const int kbeg = kidx * KCH;

  float* __restrict__ Cout = kidx ? C1 : C0;

  // A staging: thread -> (row, 4 int32 cols)
  const int ar = tid >> 4;            // 0..31
  const int ac4 = (tid & 15) * 4;     // 0..60
  const size_t a_base = (size_t)(rb * BM + ar) * NN + ac4;
  const int a_lds_off = (ar * (BK * 2) + ac4 * 2) ^ ((ar & 7) << 4);

  // B staging: 4 chunks of 16B per thread
  size_t b_goff[4]; int b_lds_off[4];
#pragma unroll
  for (int i = 0; i < 4; i++) {
    int chunk = i * 512 + tid;
    int c = chunk >> 3, slot = chunk & 7;
    b_goff[i] = (size_t)c * NN + slot * 8;
    b_lds_off[i] = (c * (BK * 2) + slot * 16) ^ ((c & 7) << 4);
  }

  int4 pfA; int4 pfB[4];
  auto issue = [&](int k0) {
    pfA = *reinterpret_cast<const int4*>(&adj[a_base + k0]);
#pragma unroll
    for (int i = 0; i < 4; i++)
      pfB[i] = *reinterpret_cast<const int4*>(&XsT[b_goff[i] + k0]);
  };
  auto commit = [&]() {
    ushort4 ab;
    ab.x = pfA.x > 0 ? 0x3F80 : 0;
    ab.y = pfA.y > 0 ? 0x3F80 : 0;
    ab.z = pfA.z > 0 ? 0x3F80 : 0;
    ab.w = pfA.w > 0 ? 0x3F80 : 0;
    *reinterpret_cast<ushort4*>(Alds + a_lds_off) = ab;
#pragma unroll
    for (int i = 0; i < 4; i++)
      *reinterpret_cast<int4*>(Blds + b_lds_off[i]) = pfB[i];
  };

  f32x4 acc[4] = {{0,0,0,0},{0,0,0,0},{0,0,0,0},{0,0,0,0}};
  f32x4 accD = {0, 0, 0, 0};

  const int arow = wrow * 16 + (lane & 15);
  const int kslot = (lane >> 4) * 16;     // byte offset of 8-bf16 chunk

  issue(kbeg);
  commit();
  __syncthreads();

  for (int t = 0; t < NT; t++) {
    if (t + 1 < NT) issue(kbeg + (t + 1) * BK);
#pragma unroll
    for (int kk = 0; kk < 2; kk++) {
      bf16x8 af = *reinterpret_cast<const bf16x8*>(
          Alds + ((arow * (BK * 2) + kk * 64 + kslot) ^ ((arow & 7) << 4)));
#pragma unroll
      for (int n = 0; n < 4; n++) {
        int c = wcol * 64 + n * 16 + (lane & 15);
        bf16x8 bfr = *reinterpret_cast<const bf16x8*>(
            Blds + ((c * (BK * 2) + kk * 64 + kslot) ^ ((c & 7) << 4)));
        acc[n] = __builtin_amdgcn_mfma_f32_16x16x32_bf16(af, bfr, acc[n], 0, 0, 0);
      }
      if (wcol == 0) {
        bf16x8 sv = {0, 0, 0, 0, 0, 0, 0, 0};
        if ((lane & 15) == 0)
          sv = *reinterpret_cast<const bf16x8*>(
              &sT[kbeg + t * BK + kk * 32 + (lane >> 4) * 8]);
        accD = __builtin_amdgcn_mfma_f32_16x16x32_bf16(af, sv, accD, 0, 0, 0);
      }
    }
    __syncthreads();
    if (t + 1 < NT) { commit(); __syncthreads(); }
  }

  // write numerator partial (C layout: col = lane&15, row = (lane>>4)*4 + q)
  const int row0 = rb * BM + wrow * 16 + (lane >> 4) * 4;
#pragma unroll
  for (int n = 0; n < 4; n++) {
    int col = wcol * 64 + n * 16 + (lane & 15);
#pragma unroll
    for (int q = 0; q < 4; q++)
      Cout[(size_t)(row0 + q) * DF + col] = acc[n][q];
  }
  if (wcol == 0 && (lane & 15) == 0) {
#pragma unroll
    for (int q = 0; q < 4; q++)
      denomPart[kidx * NN + row0 + q] = accD[q];
  }
}

// ---- kernel 6: out = (C0 + C1) / denom   (in place: C0 == d_out)
__global__ void k_norm(float* __restrict__ out, const float* __restrict__ C1,
                       const float* __restrict__ denomPart) {
  int e4 = blockIdx.x * 256 + threadIdx.x;      // 0 .. 524287
  size_t base = (size_t)e4 * 4;
  int row = (int)(base >> 8);
  float4 a = *reinterpret_cast<const float4*>(&out[base]);
  float4 b = *reinterpret_cast<const float4*>(&C1[base]);
  float inv = 1.0f / (denomPart[row] + denomPart[NN + row]);
  float4 r;
  r.x = (a.x + b.x) * inv;
  r.y = (a.y + b.y) * inv;
  r.z = (a.z + b.z) * inv;
  r.w = (a.w + b.w) * inv;
  *reinterpret_cast<float4*>(&out[base]) = r;
}

extern "C" void kernel_launch(void* const* d_in, const int* in_sizes, int n_in,
                              void* d_out, int out_size, void* d_ws, size_t ws_size,
                              hipStream_t stream) {
  const float* input = (const float*)d_in[0];
  const int* adj = (const int*)d_in[1];
  const float* A = (const float*)d_in[2];
  float* out = (float*)d_out;

  char* ws = (char*)d_ws;
  float* h2 = (float*)(ws + 0);                         // 32 KB
  float* Mv = (float*)(ws + 32768);                     // 256 B
  float* sF = (float*)(ws + 33024);                     // 32 KB
  unsigned short* sT = (unsigned short*)(ws + 65792);   // 16 KB
  unsigned short* XsT = (unsigned short*)(ws + 82176);  // 4 MB
  float* C1 = (float*)(ws + 82176 + 4194304);           // 8 MB
  float* denomPart = (float*)(ws + 82176 + 4194304 + 8388608);  // 64 KB

  k_h2<<<dim3(NN / 4), dim3(256), 0, stream>>>(input, A, h2);
  k_max<<<dim3(1), dim3(256), 0, stream>>>(h2, Mv);
  k_s<<<dim3(NN / 256), dim3(256), 0, stream>>>(h2, Mv, sF, sT);
  k_xst<<<dim3((NN / 64) * (DF / 64)), dim3(256), 0, stream>>>(input, sF, XsT);
  k_gemm<<<dim3((NN / BM) * KSPLIT), dim3(512), 0, stream>>>(adj, XsT, sT, out, C1,
                                                             denomPart);
  k_norm<<<dim3(NN * DF / 1024), dim3(256), 0, stream>>>(out, C1, denomPart);
}

// Round 3
// 496.298 us; speedup vs baseline: 1.3732x; 1.3721x over previous
//
#include <hip/hip_runtime.h>
#include <hip/hip_bf16.h>
#include <stdint.h>

typedef __attribute__((ext_vector_type(8))) short bf16x8;
typedef __attribute__((ext_vector_type(4))) float f32x4;

#define NN 8192
#define DF 256
#define BM 32
#define BK 64
#define KSPLIT 2
#define KCH (NN / KSPLIT)
#define NT (KCH / BK)            // 64
#define TILE_BYTES (DF * BK * 2) // 32768 per swizzled B tile

static __device__ __forceinline__ unsigned short f2bf(float f) {
  union { float f; unsigned u; } v; v.f = f;
  unsigned r = (v.u + 0x7FFFu + ((v.u >> 16) & 1u)) >> 16;
  return (unsigned short)r;
}

static __device__ __forceinline__ void gl_lds16(const char* g, char* l) {
  __builtin_amdgcn_global_load_lds(
      (const __attribute__((address_space(1))) void*)g,
      (__attribute__((address_space(3))) void*)l, 16, 0, 0);
}

// ---- kernel 1: h2[j] = dot(input[j,:], A[0:256])  (one wave per row)
__global__ void k_h2(const float* __restrict__ input, const float* __restrict__ A,
                     float* __restrict__ h2) {
  int gw = (blockIdx.x * blockDim.x + threadIdx.x) >> 6;
  int lane = threadIdx.x & 63;
  float4 x = *reinterpret_cast<const float4*>(&input[(size_t)gw * DF + lane * 4]);
  float4 a = *reinterpret_cast<const float4*>(&A[lane * 4]);
  float p = x.x * a.x + x.y * a.y + x.z * a.z + x.w * a.w;
#pragma unroll
  for (int off = 32; off > 0; off >>= 1) p += __shfl_down(p, off, 64);
  if (lane == 0) h2[gw] = p;
}

// ---- kernel 2: M = max(h2)
__global__ void k_max(const float* __restrict__ h2, float* __restrict__ Mout) {
  __shared__ float sm[4];
  float m = -3.0e38f;
  for (int i = threadIdx.x; i < NN; i += 256) m = fmaxf(m, h2[i]);
#pragma unroll
  for (int off = 32; off > 0; off >>= 1) m = fmaxf(m, __shfl_down(m, off, 64));
  int lane = threadIdx.x & 63, wid = threadIdx.x >> 6;
  if (lane == 0) sm[wid] = m;
  __syncthreads();
  if (threadIdx.x == 0)
    Mout[0] = fmaxf(fmaxf(sm[0], sm[1]), fmaxf(sm[2], sm[3]));
}

// ---- kernel 3: sF (fp32) and sT (bf16)
__global__ void k_s(const float* __restrict__ h2, const float* __restrict__ Mp,
                    float* __restrict__ sF, unsigned short* __restrict__ sT) {
  int j = blockIdx.x * 256 + threadIdx.x;
  float s = expf(h2[j] - Mp[0]);
  sF[j] = s;
  sT[j] = f2bf(s);
}

// ---- kernel 4: XsT pre-swizzled tiles.
// Element B[c][j] (c=0..255 feature, j=0..8191 source row) lives at
// byte tile(j>>6)*32768 + ((c*128 + (j&63)*2) ^ ((c&7)<<4)).
__global__ void k_xst(const float* __restrict__ input, const float* __restrict__ sF,
                      unsigned short* __restrict__ XsT) {
  int b = blockIdx.x;
  int jb = b >> 2, cb = b & 3;
  int t = threadIdx.x;
  int j0l = (t & 15) * 4;            // local j within tile, 0..60
  int c0 = cb * 64 + (t >> 4) * 4;
  int j0 = jb * 64 + j0l;
  float4 x[4]; float s[4];
#pragma unroll
  for (int ii = 0; ii < 4; ii++) {
    x[ii] = *reinterpret_cast<const float4*>(&input[(size_t)(j0 + ii) * DF + c0]);
    s[ii] = sF[j0 + ii];
  }
#pragma unroll
  for (int q = 0; q < 4; q++) {
    int c = c0 + q;
    ushort4 o;
    o.x = f2bf(reinterpret_cast<const float*>(&x[0])[q] * s[0]);
    o.y = f2bf(reinterpret_cast<const float*>(&x[1])[q] * s[1]);
    o.z = f2bf(reinterpret_cast<const float*>(&x[2])[q] * s[2]);
    o.w = f2bf(reinterpret_cast<const float*>(&x[3])[q] * s[3]);
    size_t idx = (size_t)jb * (TILE_BYTES / 2) +
                 (((c * 128 + j0l * 2) ^ ((c & 7) << 4)) >> 1);
    *reinterpret_cast<ushort4*>(&XsT[idx]) = o;
  }
}

// ---- kernel 5: numerator partials (+ fused denominator) via MFMA
__global__ __launch_bounds__(512, 4) void k_gemm(
    const int* __restrict__ adj, const char* __restrict__ XsTb,
    const unsigned short* __restrict__ sT, float* __restrict__ C0,
    float* __restrict__ C1, float* __restrict__ denomPart) {
  __shared__ __align__(16) char Bl[2][TILE_BYTES];   // 64 KB double buffer

  const int tid = threadIdx.x;
  const int lane = tid & 63;
  const int wid = tid >> 6;
  const int wrow = wid >> 2;   // 0..1
  const int wcol = wid & 3;    // 0..3
  const int l15 = lane & 15;
  const int l4 = (lane >> 4) & 3;

  // bijective XCD swizzle: 512 wgs, 8 XCDs, 64 per XCD; group kidx per XCD half
  int bx = blockIdx.x;
  int swz = (bx & 7) * 64 + (bx >> 3);
  const int kidx = swz >> 8;
  const int rb = swz & 255;
  const int kbeg = kidx * KCH;
  float* __restrict__ Cout = kidx ? C1 : C0;

  // A (adj) direct-load addressing: lane's fragment rows/cols
  const int arow = rb * BM + wrow * 16 + l15;
  const int64_t a_base = (int64_t)arow * NN + kbeg + l4 * 8;

  int4 pa[4], pb[4];
  f32x4 acc[4] = {{0,0,0,0},{0,0,0,0},{0,0,0,0},{0,0,0,0}};
  f32x4 accD = {0, 0, 0, 0};

  auto stageB = [&](int b, int t) {
    const char* src = XsTb + (int64_t)(kidx * NT + t) * TILE_BYTES +
                      wid * 1024 + (size_t)lane * 16;
    char* dst = &Bl[b][wid * 1024];
#pragma unroll
    for (int r = 0; r < 4; ++r)
      gl_lds16(src + r * 8192, dst + r * 8192);
  };
  auto loadA = [&](int4* dst, int t) {
    const int* p = adj + a_base + t * BK;
    dst[0] = *reinterpret_cast<const int4*>(p);       // kk0 e0..3
    dst[1] = *reinterpret_cast<const int4*>(p + 4);   // kk0 e4..7
    dst[2] = *reinterpret_cast<const int4*>(p + 32);  // kk1 e0..3
    dst[3] = *reinterpret_cast<const int4*>(p + 36);  // kk1 e4..7
  };
  auto compute = [&](int b, const int4* pav, int t) {
#pragma unroll
    for (int kk = 0; kk < 2; kk++) {
      union { unsigned u[4]; bf16x8 v; } A;
      const int4 v0 = pav[2 * kk], v1 = pav[2 * kk + 1];
      A.u[0] = (unsigned)(v0.x + (v0.y << 16)) * 0x3F80u;
      A.u[1] = (unsigned)(v0.z + (v0.w << 16)) * 0x3F80u;
      A.u[2] = (unsigned)(v1.x + (v1.y << 16)) * 0x3F80u;
      A.u[3] = (unsigned)(v1.z + (v1.w << 16)) * 0x3F80u;
      bf16x8 sv = *reinterpret_cast<const bf16x8*>(
          &sT[kbeg + t * BK + kk * 32 + l4 * 8]);
      accD = __builtin_amdgcn_mfma_f32_16x16x32_bf16(A.v, sv, accD, 0, 0, 0);
#pragma unroll
      for (int n = 0; n < 4; n++) {
        int c = wcol * 64 + n * 16 + l15;
        const char* addr =
            &Bl[b][(c * 128 + kk * 64 + l4 * 16) ^ ((c & 7) << 4)];
        bf16x8 bfr = *reinterpret_cast<const bf16x8*>(addr);
        acc[n] = __builtin_amdgcn_mfma_f32_16x16x32_bf16(A.v, bfr, acc[n], 0, 0, 0);
      }
    }
  };

  stageB(0, 0);
  loadA(pa, 0);
  asm volatile("s_waitcnt vmcnt(0)" ::: "memory");
  __syncthreads();

  for (int it = 0; it < NT / 2; ++it) {
    const int t0 = 2 * it;
    stageB(1, t0 + 1);
    loadA(pb, t0 + 1);
    compute(0, pa, t0);
    asm volatile("s_waitcnt vmcnt(0)" ::: "memory");
    __syncthreads();
    if (it + 1 < NT / 2) {
      stageB(0, t0 + 2);
      loadA(pa, t0 + 2);
    }
    compute(1, pb, t0 + 1);
    asm volatile("s_waitcnt vmcnt(0)" ::: "memory");
    __syncthreads();
  }

  // epilogue: C/D layout col=lane&15, row=(lane>>4)*4+q
  const int row0 = rb * BM + wrow * 16 + l4 * 4;
#pragma unroll
  for (int n = 0; n < 4; n++) {
    int col = wcol * 64 + n * 16 + l15;
#pragma unroll
    for (int q = 0; q < 4; q++)
      Cout[(size_t)(row0 + q) * DF + col] = acc[n][q];
  }
  if (wcol == 0 && l15 == 0) {
#pragma unroll
    for (int q = 0; q < 4; q++)
      denomPart[kidx * NN + row0 + q] = accD[q];
  }
}

// ---- kernel 6: out = (C0 + C1) / denom   (in place: C0 == d_out)
__global__ void k_norm(float* __restrict__ out, const float* __restrict__ C1,
                       const float* __restrict__ denomPart) {
  int e4 = blockIdx.x * 256 + threadIdx.x;
  size_t base = (size_t)e4 * 4;
  int row = (int)(base >> 8);
  float4 a = *reinterpret_cast<const float4*>(&out[base]);
  float4 b = *reinterpret_cast<const float4*>(&C1[base]);
  float inv = 1.0f / (denomPart[row] + denomPart[NN + row]);
  float4 r;
  r.x = (a.x + b.x) * inv;
  r.y = (a.y + b.y) * inv;
  r.z = (a.z + b.z) * inv;
  r.w = (a.w + b.w) * inv;
  *reinterpret_cast<float4*>(&out[base]) = r;
}

extern "C" void kernel_launch(void* const* d_in, const int* in_sizes, int n_in,
                              void* d_out, int out_size, void* d_ws, size_t ws_size,
                              hipStream_t stream) {
  const float* input = (const float*)d_in[0];
  const int* adj = (const int*)d_in[1];
  const float* A = (const float*)d_in[2];
  float* out = (float*)d_out;

  char* ws = (char*)d_ws;
  float* h2 = (float*)(ws + 0);                         // 32 KB
  float* Mv = (float*)(ws + 32768);                     // 256 B
  float* sF = (float*)(ws + 33024);                     // 32 KB
  unsigned short* sT = (unsigned short*)(ws + 65792);   // 16 KB
  char* XsTb = (char*)(ws + 82176);                     // 4 MB (swizzled tiles)
  float* C1 = (float*)(ws + 82176 + 4194304);           // 8 MB
  float* denomPart = (float*)(ws + 82176 + 4194304 + 8388608);  // 64 KB

  k_h2<<<dim3(NN / 4), dim3(256), 0, stream>>>(input, A, h2);
  k_max<<<dim3(1), dim3(256), 0, stream>>>(h2, Mv);
  k_s<<<dim3(NN / 256), dim3(256), 0, stream>>>(h2, Mv, sF, (unsigned short*)sT);
  k_xst<<<dim3((NN / 64) * (DF / 64)), dim3(256), 0, stream>>>(input, sF,
                                                               (unsigned short*)XsTb);
  k_gemm<<<dim3((NN / BM) * KSPLIT), dim3(512), 0, stream>>>(adj, XsTb, sT, out, C1,
                                                             denomPart);
  k_norm<<<dim3(NN * DF / 1024), dim3(256), 0, stream>>>(out, C1, denomPart);
}